// Round 6
// baseline (314.563 us; speedup 1.0000x reference)
//
#include <hip/hip_runtime.h>
#include <hip/hip_bf16.h>

typedef __attribute__((ext_vector_type(8))) short short8;
typedef __attribute__((ext_vector_type(4))) float f32x4;
using bf16 = __hip_bfloat16;

#define NEG_SLOPE 0.2f
#define LN_EPS 1e-5f
#define SCAT_EPB 2048

__device__ __forceinline__ unsigned short f2bfu(float v) {
    bf16 t = __float2bfloat16(v);
    unsigned short s;
    __builtin_memcpy(&s, &t, 2);
    return s;
}
__device__ __forceinline__ short f2bf(float v) {
    bf16 t = __float2bfloat16(v);
    short s;
    __builtin_memcpy(&s, &t, 2);
    return s;
}
__device__ __forceinline__ unsigned packbf(float a, float b) {
    return (unsigned)f2bfu(a) | ((unsigned)f2bfu(b) << 16);
}
__device__ __forceinline__ float bflo(unsigned u) { return __uint_as_float(u << 16); }
__device__ __forceinline__ float bfhi(unsigned u) { return __uint_as_float(u & 0xffff0000u); }

// dtype probe: every caller computes the same answer from the first 16KB of x.
// f32 input reinterpreted as bf16 pairs has random-exponent low halves -> huge.
__device__ __forceinline__ int computeFlag(const void* x) {
    const uint4* u4 = (const uint4*)x;
    int lane = threadIdx.x & 63;
    float m = 0.f;
    for (int i = lane; i < 1024; i += 64) {        // 1024 uint4 = 8192 ushorts
        uint4 q = u4[i];
        unsigned vv[4] = {q.x, q.y, q.z, q.w};
#pragma unroll
        for (int k = 0; k < 4; ++k) {
            float a = fabsf(bflo(vv[k]));
            float b = fabsf(bfhi(vv[k]));
            m = fmaxf(m, (a == a) ? a : 1e30f);
            m = fmaxf(m, (b == b) ? b : 1e30f);
        }
    }
    for (int d = 1; d < 64; d <<= 1) m = fmaxf(m, __shfl_xor(m, d));
    return (m > 1e4f) ? 1 : 0;
}

// ---- staging: [0,256) W transpose ; 256 smalls+flag+cursors ; [257,281) va --
struct Ptr4 { const void* p[4]; };
struct Ptr14 { const void* p[14]; };
struct Ptr3 { const void* p[3]; };
struct Ptr6 { const void* p[6]; };
__global__ void stage_k(const void* __restrict__ x,
                        Ptr4 Ws, bf16* __restrict__ WT,
                        Ptr14 ptrs, bf16* __restrict__ sv,
                        Ptr3 Wv, Ptr6 av, bf16* __restrict__ vaT,
                        int* __restrict__ dtFlag, int* __restrict__ bucketCur,
                        int CAP) {
    int b = blockIdx.x;
    int f = computeFlag(x);
    if (b < 256) {
        int gid = b * 256 + threadIdx.x;            // 4*16384
        int m = gid >> 14;
        int idx = gid & 16383;
        int i = idx >> 7, j = idx & 127;
        const void* W = Ws.p[m];
        float v = f ? ((const float*)W)[idx]
                    : __bfloat162float(((const bf16*)W)[idx]);
        WT[m * 16384 + j * 128 + i] = __float2bfloat16(v);
    } else if (b == 256) {
        for (int i = threadIdx.x; i < 512; i += 256) bucketCur[i] = i * CAP;
        if (threadIdx.x == 0) dtFlag[0] = f;
        for (int k = threadIdx.x; k < 14 * 128; k += 256) {
            int t = k >> 7, i = k & 127;
            int n = (t == 12) ? 32 : 128;
            if (i < n) {
                const void* s = ptrs.p[t];
                float v = f ? ((const float*)s)[i]
                            : __bfloat162float(((const bf16*)s)[i]);
                sv[k] = __float2bfloat16(v);
            }
        }
    } else {
        int gid = (b - 257) * 256 + threadIdx.x;    // 3*16*128
        int l = gid >> 11;
        if (l >= 3) return;
        int c = (gid >> 7) & 15, k = gid & 127;
        float acc = 0.f;
        if (c < 8) {
            int hd = c & 3;
            const void* W = Wv.p[l];
            const void* a = av.p[l * 2 + (c >> 2)];
            for (int j = 0; j < 32; ++j) {
                float wv = f ? ((const float*)W)[k * 128 + hd * 32 + j]
                             : __bfloat162float(((const bf16*)W)[k * 128 + hd * 32 + j]);
                float avv = f ? ((const float*)a)[hd * 32 + j]
                              : __bfloat162float(((const bf16*)a)[hd * 32 + j]);
                acc += wv * avv;
            }
        }
        vaT[gid] = __float2bfloat16(acc);
    }
}

// ============ bucketed CSR build, fixed capacity (no count/scan) =============
// bucket b = dst>>7; region [b*CAP, (b+1)*CAP) of ebuf/colSrc.
// two-level scatter: block aggregates 2048 edges, 1 global atomic/(block,bucket)
__global__ __launch_bounds__(256) void bscatter_k(const int* __restrict__ src,
                                                  const int* __restrict__ dst,
                                                  int* bucketCur,
                                                  int* __restrict__ ebuf,
                                                  int E, int NB, int CAP) {
    __shared__ int lcnt[512], lbase[512];
    int t = threadIdx.x;
    int e0 = blockIdx.x * SCAT_EPB;
    int cnt = E - e0;
    if (cnt > SCAT_EPB) cnt = SCAT_EPB;
    for (int i = t; i < NB; i += 256) lcnt[i] = 0;
    __syncthreads();
    for (int i = t; i < cnt; i += 256)
        atomicAdd(&lcnt[dst[e0 + i] >> 7], 1);
    __syncthreads();
    for (int i = t; i < NB; i += 256) {
        int c = lcnt[i];
        lbase[i] = c ? atomicAdd(&bucketCur[i], c) : 0;
        lcnt[i] = 0;
    }
    __syncthreads();
    for (int i = t; i < cnt; i += 256) {
        int d = dst[e0 + i];
        int b = d >> 7;
        int pos = lbase[b] + atomicAdd(&lcnt[b], 1);
        if (pos < (b + 1) * CAP)               // overflow guard (never for uniform E)
            ebuf[pos] = ((d & 127) << 16) | src[e0 + i];
    }
}

// one block per bucket: LDS node histogram -> scan -> rowSE ; scatter colSrc.
// NO slack-zeroing: agg guards every colSrc read with (j+k < en).
__global__ __launch_bounds__(256) void build_k(const int* __restrict__ ebuf,
                                               const int* __restrict__ bucketCur,
                                               int* __restrict__ rowSE,
                                               int* __restrict__ colSrc,
                                               int N, int CAP) {
    int b = blockIdx.x, t = threadIdx.x;
    int base = b * CAP;
    int cnt = bucketCur[b] - base;
    if (cnt > CAP) cnt = CAP;
    __shared__ int nodeCnt[128], nodeCur[128], ws2[2];
    if (t < 128) nodeCnt[t] = 0;
    __syncthreads();
    for (int i = t; i < cnt; i += 256)
        atomicAdd(&nodeCnt[ebuf[base + i] >> 16], 1);
    __syncthreads();
    int v = 0, incl = 0;
    if (t < 128) {
        v = nodeCnt[t];
        incl = v;
        for (int d = 1; d < 64; d <<= 1) {
            int u = __shfl_up(incl, d);
            if ((t & 63) >= d) incl += u;
        }
        if ((t & 63) == 63) ws2[t >> 6] = incl;
    }
    __syncthreads();
    if (t < 128) {
        int excl = incl - v + ((t >= 64) ? ws2[0] : 0);
        int node = b * 128 + t;
        if (node < N) {
            rowSE[node * 2] = base + excl;
            rowSE[node * 2 + 1] = base + excl + v;
        }
        nodeCur[t] = excl;
    }
    __syncthreads();
    for (int i = t; i < cnt; i += 256) {
        int p = ebuf[base + i];
        int pos = base + atomicAdd(&nodeCur[p >> 16], 1);
        colSrc[pos] = (p & 0xffff) << 8;       // byte offset src*256
    }
}

// ---- MFMA dual GEMM (layer 1), persistent B, grid-stride, NO barrier. ------
// OPERAND-SWAPPED: mfma(Wfrag, Afrag) -> lane holds 4 consecutive channels
// of one row -> 8B packed-bf16 stores. wave w owns cols w*32..w*32+31.
__global__ __launch_bounds__(256) void gemm1_k(const void* __restrict__ A,
                                               const bf16* __restrict__ WT,
                                               bf16* __restrict__ out0,
                                               bf16* __restrict__ out1,
                                               const bf16* __restrict__ bias1,
                                               const bf16* __restrict__ vaT,
                                               float* __restrict__ asN,
                                               float* __restrict__ adN,
                                               int N, const int* __restrict__ flag) {
    int wave = threadIdx.x >> 6, lane = threadIdx.x & 63;
    int lm = lane & 15, lk = lane >> 4;
    const short* Ws = (const short*)WT;
    const short* Vs = (const short*)vaT;
    bool f32m = flag[0] != 0;

    short8 bw0[2][4], bw1[2][4];
#pragma unroll
    for (int ct = 0; ct < 2; ++ct) {
        int c = (wave * 2 + ct) * 16 + lm;
#pragma unroll
        for (int kk = 0; kk < 4; ++kk) {
            bw0[ct][kk] = *(const short8*)(Ws + (size_t)c * 128 + kk * 32 + lk * 8);
            bw1[ct][kk] = *(const short8*)(Ws + 16384 + (size_t)c * 128 + kk * 32 + lk * 8);
        }
    }
    short8 va8[4];
    if (wave == 0) {
#pragma unroll
        for (int kk = 0; kk < 4; ++kk)
            va8[kk] = *(const short8*)(Vs + (size_t)lm * 128 + kk * 32 + lk * 8);
    }
    float bv[2][4];
#pragma unroll
    for (int ct = 0; ct < 2; ++ct) {
        int c0 = (wave * 2 + ct) * 16 + lk * 4;
#pragma unroll
        for (int i = 0; i < 4; ++i)
            bv[ct][i] = __bfloat162float(bias1[c0 + i]);
    }

    int stride = gridDim.x * 32;
    for (int rowBase = blockIdx.x * 32; rowBase < N; rowBase += stride) {
        short8 af[2][4];
#pragma unroll
        for (int rt = 0; rt < 2; ++rt) {
            int r = rowBase + rt * 16 + lm;
            if (r >= N) r = N - 1;
            if (f32m) {
#pragma unroll
                for (int kk = 0; kk < 4; ++kk) {
                    const float* Af = (const float*)A + (size_t)r * 128 + kk * 32 + lk * 8;
                    float4 q0 = *(const float4*)(Af);
                    float4 q1 = *(const float4*)(Af + 4);
                    short8 v;
                    v[0] = f2bf(q0.x); v[1] = f2bf(q0.y); v[2] = f2bf(q0.z); v[3] = f2bf(q0.w);
                    v[4] = f2bf(q1.x); v[5] = f2bf(q1.y); v[6] = f2bf(q1.z); v[7] = f2bf(q1.w);
                    af[rt][kk] = v;
                }
            } else {
#pragma unroll
                for (int kk = 0; kk < 4; ++kk)
                    af[rt][kk] = *(const short8*)((const short*)A + (size_t)r * 128 + kk * 32 + lk * 8);
            }
        }

        f32x4 acc0[2][2], acc1[2][2];
#pragma unroll
        for (int ct = 0; ct < 2; ++ct)
#pragma unroll
            for (int rt = 0; rt < 2; ++rt) {
                acc0[ct][rt] = (f32x4){0.f, 0.f, 0.f, 0.f};
                acc1[ct][rt] = (f32x4){0.f, 0.f, 0.f, 0.f};
            }
#pragma unroll
        for (int rt = 0; rt < 2; ++rt) {
#pragma unroll
            for (int kk = 0; kk < 4; ++kk) {
                acc0[0][rt] = __builtin_amdgcn_mfma_f32_16x16x32_bf16(bw0[0][kk], af[rt][kk], acc0[0][rt], 0, 0, 0);
                acc0[1][rt] = __builtin_amdgcn_mfma_f32_16x16x32_bf16(bw0[1][kk], af[rt][kk], acc0[1][rt], 0, 0, 0);
                acc1[0][rt] = __builtin_amdgcn_mfma_f32_16x16x32_bf16(bw1[0][kk], af[rt][kk], acc1[0][rt], 0, 0, 0);
                acc1[1][rt] = __builtin_amdgcn_mfma_f32_16x16x32_bf16(bw1[1][kk], af[rt][kk], acc1[1][rt], 0, 0, 0);
            }
        }
#pragma unroll
        for (int ct = 0; ct < 2; ++ct) {
            int c0 = (wave * 2 + ct) * 16 + lk * 4;
#pragma unroll
            for (int rt = 0; rt < 2; ++rt) {
                int r = rowBase + rt * 16 + lm;
                if (r < N) {
                    uint2 pk0, pk1;
                    pk0.x = packbf(acc0[ct][rt][0], acc0[ct][rt][1]);
                    pk0.y = packbf(acc0[ct][rt][2], acc0[ct][rt][3]);
                    pk1.x = packbf(acc1[ct][rt][0] + bv[ct][0], acc1[ct][rt][1] + bv[ct][1]);
                    pk1.y = packbf(acc1[ct][rt][2] + bv[ct][2], acc1[ct][rt][3] + bv[ct][3]);
                    *(uint2*)((unsigned short*)out0 + (size_t)r * 128 + c0) = pk0;
                    *(uint2*)((unsigned short*)out1 + (size_t)r * 128 + c0) = pk1;
                }
            }
        }
        if (wave == 0) {
            f32x4 accA[2];
#pragma unroll
            for (int rt = 0; rt < 2; ++rt) accA[rt] = (f32x4){0.f, 0.f, 0.f, 0.f};
#pragma unroll
            for (int rt = 0; rt < 2; ++rt)
#pragma unroll
                for (int kk = 0; kk < 4; ++kk)
                    accA[rt] = __builtin_amdgcn_mfma_f32_16x16x32_bf16(va8[kk], af[rt][kk], accA[rt], 0, 0, 0);
            if (lk < 2) {
                float* dp = lk ? adN : asN;
#pragma unroll
                for (int rt = 0; rt < 2; ++rt) {
                    int r = rowBase + rt * 16 + lm;
                    if (r < N) *(f32x4*)(dp + (size_t)r * 4) = accA[rt];
                }
            }
        }
    }
}

// ---- MFMA GEMM (layers 2/3), persistent B, grid-stride, NO barrier. --------
__global__ __launch_bounds__(256) void gemm_k(const void* __restrict__ A,
                                              const bf16* __restrict__ WT,
                                              bf16* __restrict__ out0,
                                              const bf16* __restrict__ vaT,
                                              float* __restrict__ asN,
                                              float* __restrict__ adN,
                                              int N) {
    int wave = threadIdx.x >> 6, lane = threadIdx.x & 63;
    int lm = lane & 15, lk = lane >> 4;
    const short* Ws = (const short*)WT;
    const short* Vs = (const short*)vaT;

    short8 bw0[2][4];
#pragma unroll
    for (int ct = 0; ct < 2; ++ct) {
        int c = (wave * 2 + ct) * 16 + lm;
#pragma unroll
        for (int kk = 0; kk < 4; ++kk)
            bw0[ct][kk] = *(const short8*)(Ws + (size_t)c * 128 + kk * 32 + lk * 8);
    }
    short8 va8[4];
    if (wave == 0) {
#pragma unroll
        for (int kk = 0; kk < 4; ++kk)
            va8[kk] = *(const short8*)(Vs + (size_t)lm * 128 + kk * 32 + lk * 8);
    }

    int stride = gridDim.x * 32;
    for (int rowBase = blockIdx.x * 32; rowBase < N; rowBase += stride) {
        short8 af[2][4];
#pragma unroll
        for (int rt = 0; rt < 2; ++rt) {
            int r = rowBase + rt * 16 + lm;
            if (r >= N) r = N - 1;
#pragma unroll
            for (int kk = 0; kk < 4; ++kk)
                af[rt][kk] = *(const short8*)((const short*)A + (size_t)r * 128 + kk * 32 + lk * 8);
        }

        f32x4 acc0[2][2];
#pragma unroll
        for (int ct = 0; ct < 2; ++ct)
#pragma unroll
            for (int rt = 0; rt < 2; ++rt) acc0[ct][rt] = (f32x4){0.f, 0.f, 0.f, 0.f};
#pragma unroll
        for (int rt = 0; rt < 2; ++rt) {
#pragma unroll
            for (int kk = 0; kk < 4; ++kk) {
                acc0[0][rt] = __builtin_amdgcn_mfma_f32_16x16x32_bf16(bw0[0][kk], af[rt][kk], acc0[0][rt], 0, 0, 0);
                acc0[1][rt] = __builtin_amdgcn_mfma_f32_16x16x32_bf16(bw0[1][kk], af[rt][kk], acc0[1][rt], 0, 0, 0);
            }
        }
#pragma unroll
        for (int ct = 0; ct < 2; ++ct) {
            int c0 = (wave * 2 + ct) * 16 + lk * 4;
#pragma unroll
            for (int rt = 0; rt < 2; ++rt) {
                int r = rowBase + rt * 16 + lm;
                if (r < N) {
                    uint2 pk;
                    pk.x = packbf(acc0[ct][rt][0], acc0[ct][rt][1]);
                    pk.y = packbf(acc0[ct][rt][2], acc0[ct][rt][3]);
                    *(uint2*)((unsigned short*)out0 + (size_t)r * 128 + c0) = pk;
                }
            }
        }
        if (wave == 0) {
            f32x4 accA[2];
#pragma unroll
            for (int rt = 0; rt < 2; ++rt) accA[rt] = (f32x4){0.f, 0.f, 0.f, 0.f};
#pragma unroll
            for (int rt = 0; rt < 2; ++rt)
#pragma unroll
                for (int kk = 0; kk < 4; ++kk)
                    accA[rt] = __builtin_amdgcn_mfma_f32_16x16x32_bf16(va8[kk], af[rt][kk], accA[rt], 0, 0, 0);
            if (lk < 2) {
                float* dp = lk ? adN : asN;
#pragma unroll
                for (int rt = 0; rt < 2; ++rt) {
                    int r = rowBase + rt * 16 + lm;
                    if (r < N) *(f32x4*)(dp + (size_t)r * 4) = accA[rt];
                }
            }
        }
    }
}

// ------------- aggregation. PERSISTENT: wave-granular grid-stride -----------
// 2048 blocks x 4 waves = 8192 waves (32/CU); each wave loops over nodes.
// Per node: 4 groups x 16 lanes; depth-3 guarded gather pipeline; thin
// per-pair epilogue (channels 2*grp, 2*grp+1 per lane).
template <int MODE>
__global__ __launch_bounds__(256) void agg_k(const bf16* __restrict__ h,
                                             const float* __restrict__ asN,
                                             const float* __restrict__ adN,
                                             const int* __restrict__ rowSE,
                                             const int* __restrict__ colSrc,
                                             const bf16* __restrict__ bvec,
                                             const bf16* __restrict__ g,
                                             const bf16* __restrict__ be,
                                             void* outv, int N,
                                             const int* __restrict__ flag) {
    int wv = threadIdx.x >> 6, lane = threadIdx.x & 63;
    int grp = lane >> 4, t = lane & 15;
    int hd = t >> 2;
    const char* hbase = (const char*)h + t * 16;
    const char* abase = (const char*)asN + hd * 4;
    int f = (MODE == 3 && flag) ? flag[0] : 0;
    int nstride = gridDim.x * 4;

    for (int n = blockIdx.x * 4 + wv; n < N; n += nstride) {
        int2 se = ((const int2*)rowSE)[n];
        int st = se.x, en = se.y;
        if (en < st) en = st;

        float adn = adN[(size_t)n * 4 + hd];
        float asn_self = asN[(size_t)n * 4 + hd];
        unsigned hs = *(const unsigned*)((const char*)h + (size_t)n * 256 + t * 16 + grp * 4);

        float a[8];
#pragma unroll
        for (int k = 0; k < 8; ++k) a[k] = 0.f;
        float den = 0.f;

        int j = st + grp;
        int o0 = (j      < en) ? colSrc[j]      : 0;
        int o1 = (j + 4  < en) ? colSrc[j + 4]  : 0;
        int o2 = (j + 8  < en) ? colSrc[j + 8]  : 0;
        int o3 = (j + 12 < en) ? colSrc[j + 12] : 0;
        float av0 = *(const float*)(abase + (o0 >> 4));
        uint4 hq0 = *(const uint4*)(hbase + o0);
        float av1 = *(const float*)(abase + (o1 >> 4));
        uint4 hq1 = *(const uint4*)(hbase + o1);
        float av2 = *(const float*)(abase + (o2 >> 4));
        uint4 hq2 = *(const uint4*)(hbase + o2);
        for (; j < en; j += 4) {
            int o4 = (j + 16 < en) ? colSrc[j + 16] : 0;
            float av3 = *(const float*)(abase + (o3 >> 4));
            uint4 hq3 = *(const uint4*)(hbase + o3);
            float e = av0 + adn;
            float w = __expf(fmaxf(e, NEG_SLOPE * e));
            den += w;
            a[0] += w * bflo(hq0.x); a[1] += w * bfhi(hq0.x);
            a[2] += w * bflo(hq0.y); a[3] += w * bfhi(hq0.y);
            a[4] += w * bflo(hq0.z); a[5] += w * bfhi(hq0.z);
            a[6] += w * bflo(hq0.w); a[7] += w * bfhi(hq0.w);
            o3 = o4;
            av0 = av1; hq0 = hq1;
            av1 = av2; hq1 = hq2;
            av2 = av3; hq2 = hq3;
        }

#pragma unroll
        for (int k = 0; k < 8; ++k) {
            a[k] += __shfl_xor(a[k], 16);
            a[k] += __shfl_xor(a[k], 32);
        }
        den += __shfl_xor(den, 16);
        den += __shfl_xor(den, 32);

        float es = asn_self + adn;
        float wsf = __expf(fmaxf(es, NEG_SLOPE * es));
        den += wsf;

        float s0 = (grp & 1) ? a[2] : a[0];
        float s1 = (grp & 1) ? a[3] : a[1];
        float s2 = (grp & 1) ? a[6] : a[4];
        float s3 = (grp & 1) ? a[7] : a[5];
        float p0 = (grp & 2) ? s2 : s0;
        float p1 = (grp & 2) ? s3 : s1;

        p0 += wsf * bflo(hs);
        p1 += wsf * bfhi(hs);

        float inv = 1.f / (den + 1e-16f);
        float y0 = p0 * inv, y1 = p1 * inv;

        if (MODE == 3) {
            y0 += __shfl_xor(y0, 4); y0 += __shfl_xor(y0, 8); y0 *= 0.25f;
            y1 += __shfl_xor(y1, 4); y1 += __shfl_xor(y1, 8); y1 *= 0.25f;
            if (t < 4) {
                int oc = t * 8 + grp * 2;
                unsigned bp = *(const unsigned*)((const char*)bvec + oc * 2);
                float v0 = y0 + bflo(bp), v1 = y1 + bfhi(bp);
                if (f) {
                    *(float2*)((float*)outv + (size_t)n * 32 + oc) = make_float2(v0, v1);
                } else {
                    ((unsigned*)outv)[(size_t)n * 16 + (oc >> 1)] = packbf(v0, v1);
                }
            }
        } else {
            unsigned short* out = (unsigned short*)outv;
            int boff = t * 16 + grp * 4;
            unsigned bp = *(const unsigned*)((const char*)bvec + boff);
            y0 += bflo(bp); y1 += bfhi(bp);
            y0 = y0 > 0.f ? y0 : (__expf(y0) - 1.f);   // ELU
            y1 = y1 > 0.f ? y1 : (__expf(y1) - 1.f);
            float s = y0 + y1, q = y0 * y0 + y1 * y1;
#pragma unroll
            for (int d = 1; d < 64; d <<= 1) {
                s += __shfl_xor(s, d);
                q += __shfl_xor(q, d);
            }
            float mu = s * (1.f / 128.f);
            float var = q * (1.f / 128.f) - mu * mu;
            var = fmaxf(var, 0.f);
            float rs = rsqrtf(var + LN_EPS);
            unsigned gp = *(const unsigned*)((const char*)g + boff);
            unsigned ep = *(const unsigned*)((const char*)be + boff);
            float z0 = (y0 - mu) * rs * bflo(gp) + bflo(ep);
            float z1 = (y1 - mu) * rs * bfhi(gp) + bfhi(ep);
            char* op = (char*)out + (size_t)n * 256 + boff;
            if (MODE == 1) {                       // add skip (x@Wsk+bsk) in-place
                unsigned sk = *(const unsigned*)op;
                z0 += bflo(sk); z1 += bfhi(sk);
            }
            *(unsigned*)op = packbf(z0, z1);
        }
    }
}

extern "C" void kernel_launch(void* const* d_in, const int* in_sizes, int n_in,
                              void* d_out, int out_size, void* d_ws, size_t ws_size,
                              hipStream_t stream) {
    const void* x  = d_in[0];
    const int*  ei = (const int*)d_in[1];

    int N = in_sizes[0] / 128;
    int E = in_sizes[1] / 2;
    const int* srcI = ei;
    const int* dstI = ei + E;

    int NB = (N + 127) >> 7;
    int CAP = (E / NB + 1024 + 511) & ~511;     // fixed bucket capacity (11σ headroom)

    char* w = (char*)d_ws;
    size_t o = 0;
    auto carve = [&](size_t bytes) {
        void* p = w + o;
        o += (bytes + 255) & ~(size_t)255;
        return p;
    };
    int*  dtFlag = (int*)carve(256);
    bf16* WTall = (bf16*)carve(4 * 16384 * 2);
    bf16* sv   = (bf16*)carve(14 * 128 * 2);
    bf16* vaT  = (bf16*)carve(3 * 16 * 128 * 2);
    bf16* hB   = (bf16*)carve((size_t)N * 128 * 2);
    bf16* xB   = (bf16*)carve((size_t)N * 128 * 2);
    float* asN = (float*)carve((size_t)N * 4 * 4);
    float* adN = (float*)carve((size_t)N * 4 * 4);
    int* rowSE = (int*)carve((size_t)N * 2 * 4);
    int* colSrc= (int*)carve((size_t)NB * CAP * 4 + 128);
    int* ebuf  = (int*)carve((size_t)NB * CAP * 4);
    int* bucketCur = (int*)carve(512 * 4);

    Ptr4 wp;
    wp.p[0] = d_in[2];  wp.p[1] = d_in[18];
    wp.p[2] = d_in[8];  wp.p[3] = d_in[14];
    Ptr14 ptrs;
    ptrs.p[0] = d_in[3];  ptrs.p[1] = d_in[4];  ptrs.p[2] = d_in[5];
    ptrs.p[3] = d_in[6];  ptrs.p[4] = d_in[7];
    ptrs.p[5] = d_in[9];  ptrs.p[6] = d_in[10]; ptrs.p[7] = d_in[11];
    ptrs.p[8] = d_in[12]; ptrs.p[9] = d_in[13];
    ptrs.p[10] = d_in[15]; ptrs.p[11] = d_in[16]; ptrs.p[12] = d_in[17];
    ptrs.p[13] = d_in[19];
    Ptr3 wv3;
    wv3.p[0] = d_in[2]; wv3.p[1] = d_in[8]; wv3.p[2] = d_in[14];
    Ptr6 av6;
    av6.p[0] = d_in[3];  av6.p[1] = d_in[4];
    av6.p[2] = d_in[9];  av6.p[3] = d_in[10];
    av6.p[4] = d_in[15]; av6.p[5] = d_in[16];

    // 1) staging (also computes dtype flag, inits bucket cursors)
    stage_k<<<281, 256, 0, stream>>>(x, wp, WTall, ptrs, sv, wv3, av6, vaT,
                                     dtFlag, bucketCur, CAP);

    int gb = (N + 63) / 64;     // gemm: grid-stride, 2 chunks of 32 rows/block
    int nQuads = (N + 3) / 4;
    int aggGrid = nQuads < 2048 ? nQuads : 2048;   // 8 blocks/CU = 32 waves/CU

    // 2) edge bucket-scatter (391 blocks, 1.5/CU)
    bscatter_k<<<(E + SCAT_EPB - 1) / SCAT_EPB, 256, 0, stream>>>(srcI, dstI,
                                                                  bucketCur, ebuf, E, NB, CAP);

    // 3) layer-1 dual GEMM: hB = x@W1, xB = x@Wsk+bsk, alpha1
    gemm1_k<<<gb, 256, 0, stream>>>(x, WTall, hB, xB, sv + 13 * 128,
                                    vaT, asN, adN, N, dtFlag);

    // 4) CSR finalize
    build_k<<<NB, 256, 0, stream>>>(ebuf, bucketCur, rowSE, colSrc, N, CAP);

    // 5) layer 1 agg: gathers hB; z1 (skip added) -> xB
    agg_k<1><<<aggGrid, 256, 0, stream>>>(hB, asN, adN, rowSE, colSrc,
                                          sv + 2 * 128, sv + 3 * 128, sv + 4 * 128,
                                          xB, N, dtFlag);

    // 6) layer 2 GEMM: hB = z1@W2 + alpha2
    gemm_k<<<gb, 256, 0, stream>>>(xB, WTall + 2 * 16384, hB,
                                   vaT + 2048, asN, adN, N);
    // 7) layer 2 agg: gathers hB; z2 -> xB
    agg_k<2><<<aggGrid, 256, 0, stream>>>(hB, asN, adN, rowSE, colSrc,
                                          sv + 7 * 128, sv + 8 * 128, sv + 9 * 128,
                                          xB, N, dtFlag);

    // 8) layer 3 GEMM: hB = z2@W3 + alpha3
    gemm_k<<<gb, 256, 0, stream>>>(xB, WTall + 3 * 16384, hB,
                                   vaT + 4096, asN, adN, N);
    // 9) layer 3 agg (mean over heads) -> d_out
    agg_k<3><<<aggGrid, 256, 0, stream>>>(hB, asN, adN, rowSE, colSrc,
                                          sv + 12 * 128, nullptr, nullptr,
                                          d_out, N, dtFlag);
}

// Round 7
// 303.709 us; speedup vs baseline: 1.0357x; 1.0357x over previous
//
#include <hip/hip_runtime.h>
#include <hip/hip_bf16.h>

typedef __attribute__((ext_vector_type(8))) short short8;
typedef __attribute__((ext_vector_type(4))) float f32x4;
using bf16 = __hip_bfloat16;

#define NEG_SLOPE 0.2f
#define LN_EPS 1e-5f
#define SCAT_EPB 2048

__device__ __forceinline__ unsigned short f2bfu(float v) {
    bf16 t = __float2bfloat16(v);
    unsigned short s;
    __builtin_memcpy(&s, &t, 2);
    return s;
}
__device__ __forceinline__ short f2bf(float v) {
    bf16 t = __float2bfloat16(v);
    short s;
    __builtin_memcpy(&s, &t, 2);
    return s;
}
__device__ __forceinline__ unsigned packbf(float a, float b) {
    return (unsigned)f2bfu(a) | ((unsigned)f2bfu(b) << 16);
}
__device__ __forceinline__ float bflo(unsigned u) { return __uint_as_float(u << 16); }
__device__ __forceinline__ float bfhi(unsigned u) { return __uint_as_float(u & 0xffff0000u); }

// dtype probe: every caller computes the same answer from the first 16KB of x.
// f32 input reinterpreted as bf16 pairs has random-exponent low halves -> huge.
__device__ __forceinline__ int computeFlag(const void* x) {
    const uint4* u4 = (const uint4*)x;
    int lane = threadIdx.x & 63;
    float m = 0.f;
    for (int i = lane; i < 1024; i += 64) {        // 1024 uint4 = 8192 ushorts
        uint4 q = u4[i];
        unsigned vv[4] = {q.x, q.y, q.z, q.w};
#pragma unroll
        for (int k = 0; k < 4; ++k) {
            float a = fabsf(bflo(vv[k]));
            float b = fabsf(bfhi(vv[k]));
            m = fmaxf(m, (a == a) ? a : 1e30f);
            m = fmaxf(m, (b == b) ? b : 1e30f);
        }
    }
    for (int d = 1; d < 64; d <<= 1) m = fmaxf(m, __shfl_xor(m, d));
    return (m > 1e4f) ? 1 : 0;
}

// ---- staging: [0,256) W transpose ; 256 smalls+flag+cursors ; [257,281) va --
struct Ptr4 { const void* p[4]; };
struct Ptr14 { const void* p[14]; };
struct Ptr3 { const void* p[3]; };
struct Ptr6 { const void* p[6]; };
__global__ void stage_k(const void* __restrict__ x,
                        Ptr4 Ws, bf16* __restrict__ WT,
                        Ptr14 ptrs, bf16* __restrict__ sv,
                        Ptr3 Wv, Ptr6 av, bf16* __restrict__ vaT,
                        int* __restrict__ dtFlag, int* __restrict__ bucketCur,
                        int CAP) {
    int b = blockIdx.x;
    int f = computeFlag(x);
    if (b < 256) {
        int gid = b * 256 + threadIdx.x;            // 4*16384
        int m = gid >> 14;
        int idx = gid & 16383;
        int i = idx >> 7, j = idx & 127;
        const void* W = Ws.p[m];
        float v = f ? ((const float*)W)[idx]
                    : __bfloat162float(((const bf16*)W)[idx]);
        WT[m * 16384 + j * 128 + i] = __float2bfloat16(v);
    } else if (b == 256) {
        for (int i = threadIdx.x; i < 512; i += 256) bucketCur[i] = i * CAP;
        if (threadIdx.x == 0) dtFlag[0] = f;
        for (int k = threadIdx.x; k < 14 * 128; k += 256) {
            int t = k >> 7, i = k & 127;
            int n = (t == 12) ? 32 : 128;
            if (i < n) {
                const void* s = ptrs.p[t];
                float v = f ? ((const float*)s)[i]
                            : __bfloat162float(((const bf16*)s)[i]);
                sv[k] = __float2bfloat16(v);
            }
        }
    } else {
        int gid = (b - 257) * 256 + threadIdx.x;    // 3*16*128
        int l = gid >> 11;
        if (l >= 3) return;
        int c = (gid >> 7) & 15, k = gid & 127;
        float acc = 0.f;
        if (c < 8) {
            int hd = c & 3;
            const void* W = Wv.p[l];
            const void* a = av.p[l * 2 + (c >> 2)];
            for (int j = 0; j < 32; ++j) {
                float wv = f ? ((const float*)W)[k * 128 + hd * 32 + j]
                             : __bfloat162float(((const bf16*)W)[k * 128 + hd * 32 + j]);
                float avv = f ? ((const float*)a)[hd * 32 + j]
                              : __bfloat162float(((const bf16*)a)[hd * 32 + j]);
                acc += wv * avv;
            }
        }
        vaT[gid] = __float2bfloat16(acc);
    }
}

// ===== MEGA dispatch: blocks [0,scatB) = bucketed edge scatter (FIRST, so
// the latency-bound half starts immediately), blocks [scatB, scatB+gb) =
// layer-1 dual GEMM. Halves are fully independent; they overlap on the CUs.
__global__ __launch_bounds__(256) void mega1_k(
        const void* __restrict__ A, const bf16* __restrict__ WT,
        bf16* __restrict__ out0, bf16* __restrict__ out1,
        const bf16* __restrict__ bias1, const bf16* __restrict__ vaT,
        float* __restrict__ asN, float* __restrict__ adN,
        int N, const int* __restrict__ flag, int scatB, int gb,
        const int* __restrict__ src, const int* __restrict__ dst,
        int* bucketCur, int* __restrict__ ebuf, int E, int NB, int CAP) {
    __shared__ int lcnt[512], lbase[512];
    if ((int)blockIdx.x < scatB) {
        // ---------------- bscatter: 2-level bucket scatter ------------------
        int t = threadIdx.x;
        int e0 = (int)blockIdx.x * SCAT_EPB;
        int cnt = E - e0;
        if (cnt > SCAT_EPB) cnt = SCAT_EPB;
        for (int i = t; i < NB; i += 256) lcnt[i] = 0;
        __syncthreads();
        for (int i = t; i < cnt; i += 256)
            atomicAdd(&lcnt[dst[e0 + i] >> 7], 1);
        __syncthreads();
        for (int i = t; i < NB; i += 256) {
            int c = lcnt[i];
            lbase[i] = c ? atomicAdd(&bucketCur[i], c) : 0;
            lcnt[i] = 0;
        }
        __syncthreads();
        for (int i = t; i < cnt; i += 256) {
            int d = dst[e0 + i];
            int b = d >> 7;
            int pos = lbase[b] + atomicAdd(&lcnt[b], 1);
            if (pos < (b + 1) * CAP)           // overflow guard
                ebuf[pos] = ((d & 127) << 16) | src[e0 + i];
        }
        return;
    }
    // ---------------- dual GEMM (operand-swapped MFMA) ----------------------
    int wave = threadIdx.x >> 6, lane = threadIdx.x & 63;
    int lm = lane & 15, lk = lane >> 4;
    const short* Ws = (const short*)WT;
    const short* Vs = (const short*)vaT;
    bool f32m = flag[0] != 0;

    short8 bw0[2][4], bw1[2][4];
#pragma unroll
    for (int ct = 0; ct < 2; ++ct) {
        int c = (wave * 2 + ct) * 16 + lm;
#pragma unroll
        for (int kk = 0; kk < 4; ++kk) {
            bw0[ct][kk] = *(const short8*)(Ws + (size_t)c * 128 + kk * 32 + lk * 8);
            bw1[ct][kk] = *(const short8*)(Ws + 16384 + (size_t)c * 128 + kk * 32 + lk * 8);
        }
    }
    short8 va8[4];
    if (wave == 0) {
#pragma unroll
        for (int kk = 0; kk < 4; ++kk)
            va8[kk] = *(const short8*)(Vs + (size_t)lm * 128 + kk * 32 + lk * 8);
    }
    float bv[2][4];
#pragma unroll
    for (int ct = 0; ct < 2; ++ct) {
        int c0 = (wave * 2 + ct) * 16 + lk * 4;
#pragma unroll
        for (int i = 0; i < 4; ++i)
            bv[ct][i] = __bfloat162float(bias1[c0 + i]);
    }

    int stride = gb * 32;
    for (int rowBase = ((int)blockIdx.x - scatB) * 32; rowBase < N; rowBase += stride) {
        short8 af[2][4];
#pragma unroll
        for (int rt = 0; rt < 2; ++rt) {
            int r = rowBase + rt * 16 + lm;
            if (r >= N) r = N - 1;
            if (f32m) {
#pragma unroll
                for (int kk = 0; kk < 4; ++kk) {
                    const float* Af = (const float*)A + (size_t)r * 128 + kk * 32 + lk * 8;
                    float4 q0 = *(const float4*)(Af);
                    float4 q1 = *(const float4*)(Af + 4);
                    short8 v;
                    v[0] = f2bf(q0.x); v[1] = f2bf(q0.y); v[2] = f2bf(q0.z); v[3] = f2bf(q0.w);
                    v[4] = f2bf(q1.x); v[5] = f2bf(q1.y); v[6] = f2bf(q1.z); v[7] = f2bf(q1.w);
                    af[rt][kk] = v;
                }
            } else {
#pragma unroll
                for (int kk = 0; kk < 4; ++kk)
                    af[rt][kk] = *(const short8*)((const short*)A + (size_t)r * 128 + kk * 32 + lk * 8);
            }
        }

        f32x4 acc0[2][2], acc1[2][2];
#pragma unroll
        for (int ct = 0; ct < 2; ++ct)
#pragma unroll
            for (int rt = 0; rt < 2; ++rt) {
                acc0[ct][rt] = (f32x4){0.f, 0.f, 0.f, 0.f};
                acc1[ct][rt] = (f32x4){0.f, 0.f, 0.f, 0.f};
            }
#pragma unroll
        for (int rt = 0; rt < 2; ++rt) {
#pragma unroll
            for (int kk = 0; kk < 4; ++kk) {
                acc0[0][rt] = __builtin_amdgcn_mfma_f32_16x16x32_bf16(bw0[0][kk], af[rt][kk], acc0[0][rt], 0, 0, 0);
                acc0[1][rt] = __builtin_amdgcn_mfma_f32_16x16x32_bf16(bw0[1][kk], af[rt][kk], acc0[1][rt], 0, 0, 0);
                acc1[0][rt] = __builtin_amdgcn_mfma_f32_16x16x32_bf16(bw1[0][kk], af[rt][kk], acc1[0][rt], 0, 0, 0);
                acc1[1][rt] = __builtin_amdgcn_mfma_f32_16x16x32_bf16(bw1[1][kk], af[rt][kk], acc1[1][rt], 0, 0, 0);
            }
        }
#pragma unroll
        for (int ct = 0; ct < 2; ++ct) {
            int c0 = (wave * 2 + ct) * 16 + lk * 4;
#pragma unroll
            for (int rt = 0; rt < 2; ++rt) {
                int r = rowBase + rt * 16 + lm;
                if (r < N) {
                    uint2 pk0, pk1;
                    pk0.x = packbf(acc0[ct][rt][0], acc0[ct][rt][1]);
                    pk0.y = packbf(acc0[ct][rt][2], acc0[ct][rt][3]);
                    pk1.x = packbf(acc1[ct][rt][0] + bv[ct][0], acc1[ct][rt][1] + bv[ct][1]);
                    pk1.y = packbf(acc1[ct][rt][2] + bv[ct][2], acc1[ct][rt][3] + bv[ct][3]);
                    *(uint2*)((unsigned short*)out0 + (size_t)r * 128 + c0) = pk0;
                    *(uint2*)((unsigned short*)out1 + (size_t)r * 128 + c0) = pk1;
                }
            }
        }
        if (wave == 0) {
            f32x4 accA[2];
#pragma unroll
            for (int rt = 0; rt < 2; ++rt) accA[rt] = (f32x4){0.f, 0.f, 0.f, 0.f};
#pragma unroll
            for (int rt = 0; rt < 2; ++rt)
#pragma unroll
                for (int kk = 0; kk < 4; ++kk)
                    accA[rt] = __builtin_amdgcn_mfma_f32_16x16x32_bf16(va8[kk], af[rt][kk], accA[rt], 0, 0, 0);
            if (lk < 2) {
                float* dp = lk ? adN : asN;
#pragma unroll
                for (int rt = 0; rt < 2; ++rt) {
                    int r = rowBase + rt * 16 + lm;
                    if (r < N) *(f32x4*)(dp + (size_t)r * 4) = accA[rt];
                }
            }
        }
    }
}

// one block per bucket: LDS node histogram -> scan -> rowSE ; scatter colSrc.
// NO slack-zeroing: agg guards every colSrc read with (j+k < en).
__global__ __launch_bounds__(256) void build_k(const int* __restrict__ ebuf,
                                               const int* __restrict__ bucketCur,
                                               int* __restrict__ rowSE,
                                               int* __restrict__ colSrc,
                                               int N, int CAP) {
    int b = blockIdx.x, t = threadIdx.x;
    int base = b * CAP;
    int cnt = bucketCur[b] - base;
    if (cnt > CAP) cnt = CAP;
    __shared__ int nodeCnt[128], nodeCur[128], ws2[2];
    if (t < 128) nodeCnt[t] = 0;
    __syncthreads();
    for (int i = t; i < cnt; i += 256)
        atomicAdd(&nodeCnt[ebuf[base + i] >> 16], 1);
    __syncthreads();
    int v = 0, incl = 0;
    if (t < 128) {
        v = nodeCnt[t];
        incl = v;
        for (int d = 1; d < 64; d <<= 1) {
            int u = __shfl_up(incl, d);
            if ((t & 63) >= d) incl += u;
        }
        if ((t & 63) == 63) ws2[t >> 6] = incl;
    }
    __syncthreads();
    if (t < 128) {
        int excl = incl - v + ((t >= 64) ? ws2[0] : 0);
        int node = b * 128 + t;
        if (node < N) {
            rowSE[node * 2] = base + excl;
            rowSE[node * 2 + 1] = base + excl + v;
        }
        nodeCur[t] = excl;
    }
    __syncthreads();
    for (int i = t; i < cnt; i += 256) {
        int p = ebuf[base + i];
        int pos = base + atomicAdd(&nodeCur[p >> 16], 1);
        colSrc[pos] = (p & 0xffff) << 8;       // byte offset src*256
    }
}

// ---- MFMA GEMM (layers 2/3), persistent B, grid-stride, NO barrier. --------
__global__ __launch_bounds__(256) void gemm_k(const void* __restrict__ A,
                                              const bf16* __restrict__ WT,
                                              bf16* __restrict__ out0,
                                              const bf16* __restrict__ vaT,
                                              float* __restrict__ asN,
                                              float* __restrict__ adN,
                                              int N) {
    int wave = threadIdx.x >> 6, lane = threadIdx.x & 63;
    int lm = lane & 15, lk = lane >> 4;
    const short* Ws = (const short*)WT;
    const short* Vs = (const short*)vaT;

    short8 bw0[2][4];
#pragma unroll
    for (int ct = 0; ct < 2; ++ct) {
        int c = (wave * 2 + ct) * 16 + lm;
#pragma unroll
        for (int kk = 0; kk < 4; ++kk)
            bw0[ct][kk] = *(const short8*)(Ws + (size_t)c * 128 + kk * 32 + lk * 8);
    }
    short8 va8[4];
    if (wave == 0) {
#pragma unroll
        for (int kk = 0; kk < 4; ++kk)
            va8[kk] = *(const short8*)(Vs + (size_t)lm * 128 + kk * 32 + lk * 8);
    }

    int stride = gridDim.x * 32;
    for (int rowBase = blockIdx.x * 32; rowBase < N; rowBase += stride) {
        short8 af[2][4];
#pragma unroll
        for (int rt = 0; rt < 2; ++rt) {
            int r = rowBase + rt * 16 + lm;
            if (r >= N) r = N - 1;
#pragma unroll
            for (int kk = 0; kk < 4; ++kk)
                af[rt][kk] = *(const short8*)((const short*)A + (size_t)r * 128 + kk * 32 + lk * 8);
        }

        f32x4 acc0[2][2];
#pragma unroll
        for (int ct = 0; ct < 2; ++ct)
#pragma unroll
            for (int rt = 0; rt < 2; ++rt) acc0[ct][rt] = (f32x4){0.f, 0.f, 0.f, 0.f};
#pragma unroll
        for (int rt = 0; rt < 2; ++rt) {
#pragma unroll
            for (int kk = 0; kk < 4; ++kk) {
                acc0[0][rt] = __builtin_amdgcn_mfma_f32_16x16x32_bf16(bw0[0][kk], af[rt][kk], acc0[0][rt], 0, 0, 0);
                acc0[1][rt] = __builtin_amdgcn_mfma_f32_16x16x32_bf16(bw0[1][kk], af[rt][kk], acc0[1][rt], 0, 0, 0);
            }
        }
#pragma unroll
        for (int ct = 0; ct < 2; ++ct) {
            int c0 = (wave * 2 + ct) * 16 + lk * 4;
#pragma unroll
            for (int rt = 0; rt < 2; ++rt) {
                int r = rowBase + rt * 16 + lm;
                if (r < N) {
                    uint2 pk;
                    pk.x = packbf(acc0[ct][rt][0], acc0[ct][rt][1]);
                    pk.y = packbf(acc0[ct][rt][2], acc0[ct][rt][3]);
                    *(uint2*)((unsigned short*)out0 + (size_t)r * 128 + c0) = pk;
                }
            }
        }
        if (wave == 0) {
            f32x4 accA[2];
#pragma unroll
            for (int rt = 0; rt < 2; ++rt) accA[rt] = (f32x4){0.f, 0.f, 0.f, 0.f};
#pragma unroll
            for (int rt = 0; rt < 2; ++rt)
#pragma unroll
                for (int kk = 0; kk < 4; ++kk)
                    accA[rt] = __builtin_amdgcn_mfma_f32_16x16x32_bf16(va8[kk], af[rt][kk], accA[rt], 0, 0, 0);
            if (lk < 2) {
                float* dp = lk ? adN : asN;
#pragma unroll
                for (int rt = 0; rt < 2; ++rt) {
                    int r = rowBase + rt * 16 + lm;
                    if (r < N) *(f32x4*)(dp + (size_t)r * 4) = accA[rt];
                }
            }
        }
    }
}

// ------------- aggregation. PERSISTENT: wave-granular grid-stride -----------
// 2048 blocks x 4 waves = 8192 waves (32/CU); each wave loops over nodes.
// Per node: 4 groups x 16 lanes; depth-3 guarded gather pipeline; thin
// per-pair epilogue (channels 2*grp, 2*grp+1 per lane).
template <int MODE>
__global__ __launch_bounds__(256) void agg_k(const bf16* __restrict__ h,
                                             const float* __restrict__ asN,
                                             const float* __restrict__ adN,
                                             const int* __restrict__ rowSE,
                                             const int* __restrict__ colSrc,
                                             const bf16* __restrict__ bvec,
                                             const bf16* __restrict__ g,
                                             const bf16* __restrict__ be,
                                             void* outv, int N,
                                             const int* __restrict__ flag) {
    int wv = threadIdx.x >> 6, lane = threadIdx.x & 63;
    int grp = lane >> 4, t = lane & 15;
    int hd = t >> 2;
    const char* hbase = (const char*)h + t * 16;
    const char* abase = (const char*)asN + hd * 4;
    int f = (MODE == 3 && flag) ? flag[0] : 0;
    int nstride = gridDim.x * 4;

    for (int n = blockIdx.x * 4 + wv; n < N; n += nstride) {
        int2 se = ((const int2*)rowSE)[n];
        int st = se.x, en = se.y;
        if (en < st) en = st;

        float adn = adN[(size_t)n * 4 + hd];
        float asn_self = asN[(size_t)n * 4 + hd];
        unsigned hs = *(const unsigned*)((const char*)h + (size_t)n * 256 + t * 16 + grp * 4);

        float a[8];
#pragma unroll
        for (int k = 0; k < 8; ++k) a[k] = 0.f;
        float den = 0.f;

        int j = st + grp;
        int o0 = (j      < en) ? colSrc[j]      : 0;
        int o1 = (j + 4  < en) ? colSrc[j + 4]  : 0;
        int o2 = (j + 8  < en) ? colSrc[j + 8]  : 0;
        int o3 = (j + 12 < en) ? colSrc[j + 12] : 0;
        float av0 = *(const float*)(abase + (o0 >> 4));
        uint4 hq0 = *(const uint4*)(hbase + o0);
        float av1 = *(const float*)(abase + (o1 >> 4));
        uint4 hq1 = *(const uint4*)(hbase + o1);
        float av2 = *(const float*)(abase + (o2 >> 4));
        uint4 hq2 = *(const uint4*)(hbase + o2);
        for (; j < en; j += 4) {
            int o4 = (j + 16 < en) ? colSrc[j + 16] : 0;
            float av3 = *(const float*)(abase + (o3 >> 4));
            uint4 hq3 = *(const uint4*)(hbase + o3);
            float e = av0 + adn;
            float w = __expf(fmaxf(e, NEG_SLOPE * e));
            den += w;
            a[0] += w * bflo(hq0.x); a[1] += w * bfhi(hq0.x);
            a[2] += w * bflo(hq0.y); a[3] += w * bfhi(hq0.y);
            a[4] += w * bflo(hq0.z); a[5] += w * bfhi(hq0.z);
            a[6] += w * bflo(hq0.w); a[7] += w * bfhi(hq0.w);
            o3 = o4;
            av0 = av1; hq0 = hq1;
            av1 = av2; hq1 = hq2;
            av2 = av3; hq2 = hq3;
        }

#pragma unroll
        for (int k = 0; k < 8; ++k) {
            a[k] += __shfl_xor(a[k], 16);
            a[k] += __shfl_xor(a[k], 32);
        }
        den += __shfl_xor(den, 16);
        den += __shfl_xor(den, 32);

        float es = asn_self + adn;
        float wsf = __expf(fmaxf(es, NEG_SLOPE * es));
        den += wsf;

        float s0 = (grp & 1) ? a[2] : a[0];
        float s1 = (grp & 1) ? a[3] : a[1];
        float s2 = (grp & 1) ? a[6] : a[4];
        float s3 = (grp & 1) ? a[7] : a[5];
        float p0 = (grp & 2) ? s2 : s0;
        float p1 = (grp & 2) ? s3 : s1;

        p0 += wsf * bflo(hs);
        p1 += wsf * bfhi(hs);

        float inv = 1.f / (den + 1e-16f);
        float y0 = p0 * inv, y1 = p1 * inv;

        if (MODE == 3) {
            y0 += __shfl_xor(y0, 4); y0 += __shfl_xor(y0, 8); y0 *= 0.25f;
            y1 += __shfl_xor(y1, 4); y1 += __shfl_xor(y1, 8); y1 *= 0.25f;
            if (t < 4) {
                int oc = t * 8 + grp * 2;
                unsigned bp = *(const unsigned*)((const char*)bvec + oc * 2);
                float v0 = y0 + bflo(bp), v1 = y1 + bfhi(bp);
                if (f) {
                    *(float2*)((float*)outv + (size_t)n * 32 + oc) = make_float2(v0, v1);
                } else {
                    ((unsigned*)outv)[(size_t)n * 16 + (oc >> 1)] = packbf(v0, v1);
                }
            }
        } else {
            unsigned short* out = (unsigned short*)outv;
            int boff = t * 16 + grp * 4;
            unsigned bp = *(const unsigned*)((const char*)bvec + boff);
            y0 += bflo(bp); y1 += bfhi(bp);
            y0 = y0 > 0.f ? y0 : (__expf(y0) - 1.f);   // ELU
            y1 = y1 > 0.f ? y1 : (__expf(y1) - 1.f);
            float s = y0 + y1, q = y0 * y0 + y1 * y1;
#pragma unroll
            for (int d = 1; d < 64; d <<= 1) {
                s += __shfl_xor(s, d);
                q += __shfl_xor(q, d);
            }
            float mu = s * (1.f / 128.f);
            float var = q * (1.f / 128.f) - mu * mu;
            var = fmaxf(var, 0.f);
            float rs = rsqrtf(var + LN_EPS);
            unsigned gp = *(const unsigned*)((const char*)g + boff);
            unsigned ep = *(const unsigned*)((const char*)be + boff);
            float z0 = (y0 - mu) * rs * bflo(gp) + bflo(ep);
            float z1 = (y1 - mu) * rs * bfhi(gp) + bfhi(ep);
            char* op = (char*)out + (size_t)n * 256 + boff;
            if (MODE == 1) {                       // add skip (x@Wsk+bsk) in-place
                unsigned sk = *(const unsigned*)op;
                z0 += bflo(sk); z1 += bfhi(sk);
            }
            *(unsigned*)op = packbf(z0, z1);
        }
    }
}

extern "C" void kernel_launch(void* const* d_in, const int* in_sizes, int n_in,
                              void* d_out, int out_size, void* d_ws, size_t ws_size,
                              hipStream_t stream) {
    const void* x  = d_in[0];
    const int*  ei = (const int*)d_in[1];

    int N = in_sizes[0] / 128;
    int E = in_sizes[1] / 2;
    const int* srcI = ei;
    const int* dstI = ei + E;

    int NB = (N + 127) >> 7;
    int CAP = (E / NB + 1024 + 511) & ~511;     // fixed bucket capacity (11σ headroom)

    char* w = (char*)d_ws;
    size_t o = 0;
    auto carve = [&](size_t bytes) {
        void* p = w + o;
        o += (bytes + 255) & ~(size_t)255;
        return p;
    };
    int*  dtFlag = (int*)carve(256);
    bf16* WTall = (bf16*)carve(4 * 16384 * 2);
    bf16* sv   = (bf16*)carve(14 * 128 * 2);
    bf16* vaT  = (bf16*)carve(3 * 16 * 128 * 2);
    bf16* hB   = (bf16*)carve((size_t)N * 128 * 2);
    bf16* xB   = (bf16*)carve((size_t)N * 128 * 2);
    float* asN = (float*)carve((size_t)N * 4 * 4);
    float* adN = (float*)carve((size_t)N * 4 * 4);
    int* rowSE = (int*)carve((size_t)N * 2 * 4);
    int* colSrc= (int*)carve((size_t)NB * CAP * 4 + 128);
    int* ebuf  = (int*)carve((size_t)NB * CAP * 4);
    int* bucketCur = (int*)carve(512 * 4);

    Ptr4 wp;
    wp.p[0] = d_in[2];  wp.p[1] = d_in[18];
    wp.p[2] = d_in[8];  wp.p[3] = d_in[14];
    Ptr14 ptrs;
    ptrs.p[0] = d_in[3];  ptrs.p[1] = d_in[4];  ptrs.p[2] = d_in[5];
    ptrs.p[3] = d_in[6];  ptrs.p[4] = d_in[7];
    ptrs.p[5] = d_in[9];  ptrs.p[6] = d_in[10]; ptrs.p[7] = d_in[11];
    ptrs.p[8] = d_in[12]; ptrs.p[9] = d_in[13];
    ptrs.p[10] = d_in[15]; ptrs.p[11] = d_in[16]; ptrs.p[12] = d_in[17];
    ptrs.p[13] = d_in[19];
    Ptr3 wv3;
    wv3.p[0] = d_in[2]; wv3.p[1] = d_in[8]; wv3.p[2] = d_in[14];
    Ptr6 av6;
    av6.p[0] = d_in[3];  av6.p[1] = d_in[4];
    av6.p[2] = d_in[9];  av6.p[3] = d_in[10];
    av6.p[4] = d_in[15]; av6.p[5] = d_in[16];

    // 1) staging (also computes dtype flag, inits bucket cursors)
    stage_k<<<281, 256, 0, stream>>>(x, wp, WTall, ptrs, sv, wv3, av6, vaT,
                                     dtFlag, bucketCur, CAP);

    int gb = (N + 63) / 64;     // gemm: grid-stride, 2 chunks of 32 rows/block
    int scatB = (E + SCAT_EPB - 1) / SCAT_EPB;
    int nQuads = (N + 3) / 4;
    int aggGrid = nQuads < 2048 ? nQuads : 2048;   // 8 blocks/CU = 32 waves/CU

    // 2) MEGA: edge bucket-scatter (blocks 0..scatB, FIRST) ||
    //    layer-1 dual GEMM (hB = x@W1, xB = x@Wsk+bsk, alpha1)
    mega1_k<<<scatB + gb, 256, 0, stream>>>(x, WTall, hB, xB, sv + 13 * 128,
                                            vaT, asN, adN, N, dtFlag, scatB, gb,
                                            srcI, dstI, bucketCur, ebuf, E, NB, CAP);

    // 3) CSR finalize
    build_k<<<NB, 256, 0, stream>>>(ebuf, bucketCur, rowSE, colSrc, N, CAP);

    // 4) layer 1 agg: gathers hB; z1 (skip added) -> xB
    agg_k<1><<<aggGrid, 256, 0, stream>>>(hB, asN, adN, rowSE, colSrc,
                                          sv + 2 * 128, sv + 3 * 128, sv + 4 * 128,
                                          xB, N, dtFlag);

    // 5) layer 2 GEMM: hB = z1@W2 + alpha2
    gemm_k<<<gb, 256, 0, stream>>>(xB, WTall + 2 * 16384, hB,
                                   vaT + 2048, asN, adN, N);
    // 6) layer 2 agg: gathers hB; z2 -> xB
    agg_k<2><<<aggGrid, 256, 0, stream>>>(hB, asN, adN, rowSE, colSrc,
                                          sv + 7 * 128, sv + 8 * 128, sv + 9 * 128,
                                          xB, N, dtFlag);

    // 7) layer 3 GEMM: hB = z2@W3 + alpha3
    gemm_k<<<gb, 256, 0, stream>>>(xB, WTall + 3 * 16384, hB,
                                   vaT + 4096, asN, adN, N);
    // 8) layer 3 agg (mean over heads) -> d_out
    agg_k<3><<<aggGrid, 256, 0, stream>>>(hB, asN, adN, rowSE, colSrc,
                                          sv + 12 * 128, nullptr, nullptr,
                                          d_out, N, dtFlag);
}